// Round 11
// baseline (130.350 us; speedup 1.0000x reference)
//
#include <hip/hip_runtime.h>
#include <stdint.h>

#define EPSN 1e-12f

typedef float f32x4 __attribute__((ext_vector_type(4)));
typedef float f32x16 __attribute__((ext_vector_type(16)));
typedef __bf16 bf16x8 __attribute__((ext_vector_type(8)));
typedef long long i64x2 __attribute__((ext_vector_type(2)));

// ---- bf16 helpers ----
__device__ __forceinline__ unsigned short f2bf(float f) {
  union { float f; unsigned int u; } v; v.f = f;
  unsigned int u = v.u + 0x7FFFu + ((v.u >> 16) & 1u);
  return (unsigned short)(u >> 16);
}

// f32 pair -> 2 OCP e4m3 bytes (RNE, HW convert)
__device__ __forceinline__ unsigned short f2fp8x2(float a, float b) {
  int r = __builtin_amdgcn_cvt_pk_fp8_f32(a, b, 0, false);
  return (unsigned short)(r & 0xFFFF);
}

// ---- workspace layout (BYTES) ----
// fp8 A-fragments for 16x16x32 MFMA, 4-tile groups, K padded 258->288:
//   byte = ((grp*9 + ks)*64 + lane)*32 + t*8 + j
//   value = W[o = (grp*4+t)*16 + (lane&15)][k = ks*32 + (lane>>4)*8 + j]
//   (k=258 bias, k>258 zero). grp 0..15, ks 0..8, t 0..3, j 0..7.
#define NKS9 9
#define GRPB (NKS9 * 64 * 32)        // 18432 B per group-stream
#define WQF_B 0
#define WKF_B (16 * GRPB)            // 294912
#define WVP_OFF_S (2 * 16 * GRPB / 2)  // ushort index 294912

// =====================================================================
// prep: blocks [0,512) pack wq/wk (4 o-rows each, fp8 16x16 frags);
//       [512,1536) WVt (bf16).
// =====================================================================
__global__ __launch_bounds__(256) void prep_kernel(
    const float* __restrict__ wq, const float* __restrict__ bq,
    const float* __restrict__ wk, const float* __restrict__ bk,
    const float* __restrict__ v, const float* __restrict__ wout,
    unsigned short* __restrict__ wsp) {
  uint8_t* wsp8 = (uint8_t*)wsp;
  int bid = blockIdx.x;
  if (bid < 512) {
    int isK = bid >= 256;
    int ob = (bid & 255) * 4;
    const float* w = isK ? wk : wq;
    const float* bb = isK ? bk : bq;
    uint8_t* dst = wsp8 + (isK ? WKF_B : WQF_B);
    // k 0..257 as 129 float2 per o-row
    for (int i = threadIdx.x; i < 4 * 129; i += 256) {
      int r = i / 129, q = i - r * 129;
      int o = ob + r, k = q * 2;
      float2 w2 = *(const float2*)(w + o * 258 + k);
      int grp = o >> 6, t = (o >> 4) & 3, r16 = o & 15;
      int ks = k >> 5, l4 = (k >> 3) & 3, j = k & 7;
      int lane = l4 * 16 + r16;
      *(unsigned short*)(dst + ((grp * NKS9 + ks) * 64 + lane) * 32 + t * 8 + j) =
          f2fp8x2(w2.x, w2.y);
    }
    // k 258 (bias) .. 287 (zero): 30 per o-row
    for (int i = threadIdx.x; i < 4 * 30; i += 256) {
      int r = i / 30, kk = 258 + (i - r * 30);
      int o = ob + r;
      int grp = o >> 6, t = (o >> 4) & 3, r16 = o & 15;
      int ks = kk >> 5, l4 = (kk >> 3) & 3, j = kk & 7;
      int lane = l4 * 16 + r16;
      uint8_t val = (kk == 258) ? (uint8_t)(f2fp8x2(bb[o], 0.f) & 0xFF)
                                : (uint8_t)0;
      dst[((grp * NKS9 + ks) * 64 + lane) * 32 + t * 8 + j] = val;
    }
  } else {
    int idx = (bid - 512) * 256 + threadIdx.x;
    int fc = idx & 15, m = (idx >> 4) & 63, o = idx >> 10;
    const f32x4* wo = (const f32x4*)(wout + o * 256 + fc * 16);
    const f32x4* vm = (const f32x4*)(v + m * 256 + fc * 16);
    float s = 0.f;
#pragma unroll
    for (int f = 0; f < 4; ++f) {
      f32x4 a = wo[f], bvv = vm[f];
      s += a[0]*bvv[0] + a[1]*bvv[1] + a[2]*bvv[2] + a[3]*bvv[3];
    }
    s += __shfl_xor(s, 1, 64);
    s += __shfl_xor(s, 2, 64);
    s += __shfl_xor(s, 4, 64);
    s += __shfl_xor(s, 8, 64);
    if (fc == 0) wsp[WVP_OFF_S + o * 64 + m] = f2bf(s);
  }
}

// =====================================================================
// fused v11: 16x16x32 fp8 Q/K GEMM. Per wave: 4 o-tiles x 4 px-tiles,
// 16 MFMA per K-step => per-SIMD MFMA cluster ~307 cyc > L2 latency
// (first variant whose cluster covers the per-step load latency).
// 9 K-steps per phase (K=32/step, padded 288). acc = 16 x f32x4 = 64
// AGPR. One o-tile == one memory slot m; sq lives in (lane>>4, reg).
// =====================================================================
#define PXB 64    // pixels per block
#define KP8 296   // xp8 row stride in BYTES
#define QS 66     // qbar row stride (floats); rows = sq 0..15
#define AT 72     // attnM row stride (shorts)

__global__ __launch_bounds__(1024, 4) void fused_kernel(
    const float* __restrict__ x, const float* __restrict__ pos,
    const unsigned short* __restrict__ wsp, const float* __restrict__ bout,
    float* __restrict__ out) {
  __shared__ __align__(16) uint8_t xp8[PXB * KP8];             // 18944 B
  __shared__ __align__(16) float qbarL[16 * QS];               // 4224 B
  __shared__ __align__(16) unsigned short attnM[PXB * AT];     // 9216 B
  __shared__ float boutL[256];                                 // 1024 B

  const int tid = threadIdx.x;
  const int lane = tid & 63;
  const int wid = __builtin_amdgcn_readfirstlane(tid >> 6);
  const int l15 = lane & 15, l4 = lane >> 4;
  const int P0 = blockIdx.x * PXB;
  const int b = P0 >> 12, s0 = P0 & 4095;

  const uint8_t* wsp8 = (const uint8_t*)wsp;
  // Per-wave A-stream: group = wid (tiles 4wid..4wid+3), +lane*32
  const uint8_t* wqf = wsp8 + WQF_B + wid * GRPB + lane * 32;
  const uint8_t* wkf = wsp8 + WKF_B + wid * GRPB + lane * 32;

  // ---- stage xp8[p][k] as fp8 (identical to R10) ----
  {
    const float* xrow = x + b * 256 * 4096 + s0;
    f32x4 lo[2], hi[2];
#pragma unroll
    for (int it = 0; it < 2; ++it) {
      int idx = tid + it * 1024;                  // 0..2047
      int g = idx & 15, dcol = idx >> 4;          // dcol 0..127
      lo[it] = __builtin_nontemporal_load(
          (const f32x4*)(xrow + (2 * dcol) * 4096 + 4 * g));
      hi[it] = __builtin_nontemporal_load(
          (const f32x4*)(xrow + (2 * dcol + 1) * 4096 + 4 * g));
    }
#pragma unroll
    for (int it = 0; it < 2; ++it) {
      int idx = tid + it * 1024;
      int g = idx & 15, dcol = idx >> 4;
#pragma unroll
      for (int j = 0; j < 4; ++j) {
        int pp = 4 * g + j;
        *(unsigned short*)&xp8[pp * KP8 + 2 * dcol] =
            f2fp8x2(lo[it][j], hi[it][j]);
      }
    }
    // tail: dcol 128 = (pos_y,pos_x), 129 = (1,0) bias, 130..147 = 0
    if (tid < 64 * 20) {
      int pp = tid & 63, dcol = 128 + (tid >> 6);  // dcol 128..147
      float t0 = 0.f, t1 = 0.f;
      if (dcol == 128) { t0 = pos[s0 + pp]; t1 = pos[4096 + s0 + pp]; }
      else if (dcol == 129) { t0 = 1.0f; }
      *(unsigned short*)&xp8[pp * KP8 + 2 * dcol] = f2fp8x2(t0, t1);
    }
  }
  if (tid < 256) boutL[tid] = bout[tid];
  for (int i = tid; i < 16 * QS; i += 1024) qbarL[i] = 0.f;
  __syncthreads();

  // B-fragment base pointers (one per px-tile)
  const uint8_t* bp0 = &xp8[(0 * 16 + l15) * KP8 + l4 * 8];
  const uint8_t* bp1 = &xp8[(1 * 16 + l15) * KP8 + l4 * 8];
  const uint8_t* bp2 = &xp8[(2 * 16 + l15) * KP8 + l4 * 8];
  const uint8_t* bp3 = &xp8[(3 * 16 + l15) * KP8 + l4 * 8];

#define MFMA8(Aop, B, pt) do {                                            \
    acc[0][pt] = __builtin_amdgcn_mfma_f32_16x16x32_fp8_fp8(Aop[0], B, acc[0][pt], 0, 0, 0); \
  } while (0)

// K-loop: rolled, depth-1 named prefetch. Per step: 2 ldx4 (A, 4 tiles)
// + 4 ds_read_b64 (B) + 16 MFMA (~307 cyc cluster per SIMD).
#define PHASE(WB) do {                                                    \
    const uint8_t* _p = (WB);                                             \
    i64x2 A0 = *(const i64x2*)(_p);        /* tiles 0,1 */                \
    i64x2 A1 = *(const i64x2*)(_p + 16);   /* tiles 2,3 */                \
    _Pragma("unroll 1")                                                   \
    for (int i = 0; i < NKS9; ++i) {                                      \
      i64x2 N0 = A0, N1 = A1;                                             \
      if (i + 1 < NKS9) {                                                 \
        N0 = *(const i64x2*)(_p + (i + 1) * 2048);                        \
        N1 = *(const i64x2*)(_p + (i + 1) * 2048 + 16);                   \
      }                                                                   \
      long long b0 = *(const long long*)(bp0 + i * 32);                   \
      long long b1 = *(const long long*)(bp1 + i * 32);                   \
      long long b2 = *(const long long*)(bp2 + i * 32);                   \
      long long b3 = *(const long long*)(bp3 + i * 32);                   \
      __builtin_amdgcn_s_setprio(1);                                      \
      acc[0][0] = __builtin_amdgcn_mfma_f32_16x16x32_fp8_fp8(A0[0], b0, acc[0][0], 0, 0, 0); \
      acc[0][1] = __builtin_amdgcn_mfma_f32_16x16x32_fp8_fp8(A0[0], b1, acc[0][1], 0, 0, 0); \
      acc[0][2] = __builtin_amdgcn_mfma_f32_16x16x32_fp8_fp8(A0[0], b2, acc[0][2], 0, 0, 0); \
      acc[0][3] = __builtin_amdgcn_mfma_f32_16x16x32_fp8_fp8(A0[0], b3, acc[0][3], 0, 0, 0); \
      acc[1][0] = __builtin_amdgcn_mfma_f32_16x16x32_fp8_fp8(A0[1], b0, acc[1][0], 0, 0, 0); \
      acc[1][1] = __builtin_amdgcn_mfma_f32_16x16x32_fp8_fp8(A0[1], b1, acc[1][1], 0, 0, 0); \
      acc[1][2] = __builtin_amdgcn_mfma_f32_16x16x32_fp8_fp8(A0[1], b2, acc[1][2], 0, 0, 0); \
      acc[1][3] = __builtin_amdgcn_mfma_f32_16x16x32_fp8_fp8(A0[1], b3, acc[1][3], 0, 0, 0); \
      acc[2][0] = __builtin_amdgcn_mfma_f32_16x16x32_fp8_fp8(A1[0], b0, acc[2][0], 0, 0, 0); \
      acc[2][1] = __builtin_amdgcn_mfma_f32_16x16x32_fp8_fp8(A1[0], b1, acc[2][1], 0, 0, 0); \
      acc[2][2] = __builtin_amdgcn_mfma_f32_16x16x32_fp8_fp8(A1[0], b2, acc[2][2], 0, 0, 0); \
      acc[2][3] = __builtin_amdgcn_mfma_f32_16x16x32_fp8_fp8(A1[0], b3, acc[2][3], 0, 0, 0); \
      acc[3][0] = __builtin_amdgcn_mfma_f32_16x16x32_fp8_fp8(A1[1], b0, acc[3][0], 0, 0, 0); \
      acc[3][1] = __builtin_amdgcn_mfma_f32_16x16x32_fp8_fp8(A1[1], b1, acc[3][1], 0, 0, 0); \
      acc[3][2] = __builtin_amdgcn_mfma_f32_16x16x32_fp8_fp8(A1[1], b2, acc[3][2], 0, 0, 0); \
      acc[3][3] = __builtin_amdgcn_mfma_f32_16x16x32_fp8_fp8(A1[1], b3, acc[3][3], 0, 0, 0); \
      __builtin_amdgcn_s_setprio(0);                                      \
      A0 = N0; A1 = N1;                                                   \
    }                                                                     \
  } while (0)

  // ================= q phase =================
  f32x4 acc[4][4];
#pragma unroll
  for (int t = 0; t < 4; ++t)
#pragma unroll
    for (int pt = 0; pt < 4; ++pt) acc[t][pt] = (f32x4)0.f;
  PHASE(wqf);

  // q-norm per m (= per tile t); accumulate qbar partials.
  // acc[t][pt][reg] = q[m=4wid+t][sq=l4*4+reg][pixel=pt*16+l15]
  {
    float qsum[4][4];
#pragma unroll
    for (int pt = 0; pt < 4; ++pt)
#pragma unroll
      for (int r = 0; r < 4; ++r) qsum[pt][r] = 0.f;
#pragma unroll
    for (int t = 0; t < 4; ++t) {
#pragma unroll
      for (int pt = 0; pt < 4; ++pt) {
        float s2 = 0.f;
#pragma unroll
        for (int r = 0; r < 4; ++r) s2 = fmaf(acc[t][pt][r], acc[t][pt][r], s2);
        s2 += __shfl_xor(s2, 16, 64);
        s2 += __shfl_xor(s2, 32, 64);
        float inv = 1.0f / fmaxf(sqrtf(s2), EPSN);
#pragma unroll
        for (int r = 0; r < 4; ++r) qsum[pt][r] += acc[t][pt][r] * inv;
      }
    }
#pragma unroll
    for (int pt = 0; pt < 4; ++pt)
#pragma unroll
      for (int r = 0; r < 4; ++r)
        atomicAdd(&qbarL[(l4 * 4 + r) * QS + pt * 16 + l15],
                  qsum[pt][r] * (1.0f / 64.0f));
  }
  // NO barrier: k K-loop doesn't read qbarL; barrier after it orders
  // the atomics vs the qb reads.

  // ================= k phase =================
#pragma unroll
  for (int t = 0; t < 4; ++t)
#pragma unroll
    for (int pt = 0; pt < 4; ++pt) acc[t][pt] = (f32x4)0.f;
  PHASE(wkf);
  __syncthreads();

  // attn[m][p] = sum_sq qbar[sq][p] * k[m][sq][p] / ||k[m][:][p]||
  {
    float qb[4][4];
#pragma unroll
    for (int pt = 0; pt < 4; ++pt)
#pragma unroll
      for (int r = 0; r < 4; ++r)
        qb[pt][r] = qbarL[(l4 * 4 + r) * QS + pt * 16 + l15];
#pragma unroll
    for (int t = 0; t < 4; ++t) {
#pragma unroll
      for (int pt = 0; pt < 4; ++pt) {
        float s2 = 0.f, sp = 0.f;
#pragma unroll
        for (int r = 0; r < 4; ++r) {
          s2 = fmaf(acc[t][pt][r], acc[t][pt][r], s2);
          sp = fmaf(qb[pt][r], acc[t][pt][r], sp);
        }
        s2 += __shfl_xor(s2, 16, 64);
        sp += __shfl_xor(sp, 16, 64);
        s2 += __shfl_xor(s2, 32, 64);
        sp += __shfl_xor(sp, 32, 64);
        if (l4 == 0) {
          attnM[(pt * 16 + l15) * AT + 4 * wid + t] =
              f2bf(sp / fmaxf(sqrtf(s2), EPSN));
        }
      }
    }
  }
  __syncthreads();

  // ==== epilogue: out = x + bout + WVt @ attn (bf16 32x32 MFMA) ====
  {
    const int px = lane & 31, q2 = lane >> 5;
    const int otile = wid >> 1, pxt = wid & 1;
    f32x16 e = (f32x16)0.f;
    const unsigned short* wv =
        wsp + WVP_OFF_S + (otile * 32 + px) * 64 + q2 * 8;
    const unsigned short* ab = &attnM[(pxt * 32 + px) * AT + q2 * 8];
#pragma unroll
    for (int ks = 0; ks < 4; ++ks) {
      bf16x8 av = *(const bf16x8*)(wv + ks * 16);
      bf16x8 bv = *(const bf16x8*)(ab + ks * 16);
      e = __builtin_amdgcn_mfma_f32_32x32x16_bf16(av, bv, e, 0, 0, 0);
    }
    const int p = pxt * 32 + px;
#pragma unroll
    for (int r = 0; r < 16; ++r) {
      const int o = otile * 32 + (r & 3) + ((r >> 2) << 3) + (q2 << 2);
      const int gi = (b * 256 + o) * 4096 + s0 + p;
      float xv = __builtin_nontemporal_load(&x[gi]);
      __builtin_nontemporal_store(xv + boutL[o] + e[r], &out[gi]);
    }
  }
#undef PHASE
#undef MFMA8
}

// =====================================================================
extern "C" void kernel_launch(void* const* d_in, const int* in_sizes, int n_in,
                              void* d_out, int out_size, void* d_ws, size_t ws_size,
                              hipStream_t stream) {
  const float* x    = (const float*)d_in[0];
  const float* pos  = (const float*)d_in[1];
  const float* wq   = (const float*)d_in[2];
  const float* bq   = (const float*)d_in[3];
  const float* wk   = (const float*)d_in[4];
  const float* bk   = (const float*)d_in[5];
  const float* v    = (const float*)d_in[6];
  const float* wout = (const float*)d_in[7];
  const float* bout = (const float*)d_in[8];
  float* out = (float*)d_out;
  unsigned short* wsp = (unsigned short*)d_ws;

  hipLaunchKernelGGL(prep_kernel, dim3(1536), dim3(256), 0, stream,
                     wq, bq, wk, bk, v, wout, wsp);
  hipLaunchKernelGGL(fused_kernel, dim3(256), dim3(1024), 0, stream,
                     x, pos, wsp, bout, out);
}